// Round 8
// baseline (642.560 us; speedup 1.0000x reference)
//
#include <hip/hip_runtime.h>
#include <math.h>

#define B_ 16
#define C_ 129
#define T_ 2000
#define NF_ 40
#define ED_ 64
#define K_ 16
#define TP_ 500

// workspace float offsets
#define OFF_SB2 1040     // 40     folded sconv bias
#define OFF_PWC 1088     // 3200   pw weights * pbn scale
#define OFF_PB2 4288     // 80     folded pw bias
#define OFF_WP  4368     // 1280   wx0 @ proj_w  (16x80)
#define OFF_BP  5648     // 16     wx0 @ proj_b + b0
#define OFF_W1A 6224     // 768    tconv A-frag prepack (3 mt x 64 lanes x 8 bf16)
#define OFF_SA  6992     // 1024   scan A-frag panels: A1hi,A1lo,A2hi,A2lo (4 x 512 ushort)
#define OFF_W2U 8192     // bf16 A-frag prepack of sconv weights: 396288 ushort
#define OFF_XP  1495040  // 16*500*16  per-step cell0 input projection
#define OFF_S2R 1623040  // 1.28M  raw sconv accumulator (atomicAdd target)

typedef __attribute__((ext_vector_type(8))) short s8v;
typedef __attribute__((ext_vector_type(4))) float f4v;

#define XROW 292         // xs row stride: 256 t + 24 halo + 12 left pad

__device__ __forceinline__ float elu_f(float x) {
    return x > 0.f ? x : (__expf(x) - 1.f);
}
// round-half-up fp32 -> bf16
__device__ __forceinline__ unsigned bfr(float v) {
    return (__float_as_uint(v) + 0x8000u) >> 16;
}

struct P0 {
    const float *tconv_w, *tconv_b, *tbn_g, *tbn_b, *tbn_m, *tbn_v;
    const float *sconv_b, *sbn_g, *sbn_b, *sbn_m, *sbn_v;
    const float *pw_w, *pw_b, *pbn_g, *pbn_b, *pbn_m, *pbn_v;
    const float *proj_w, *proj_b, *wx0, *b0, *L0, *ll0, *L1, *ll1, *wx1;
    float* ws;
};

__global__ __launch_bounds__(256) void k0a_setup(P0 p) {
    const int tid = blockIdx.x * 256 + threadIdx.x;
    const int stride = gridDim.x * 256;
    float* ws = p.ws;
    const float eps = 1e-5f;
    // tconv A-frag prepack (bf16): A[m=f][k=tap], K=32; tap 25 = folded bias
    for (int e = tid; e < 192; e += stride) {
        const int mt = e >> 6, L = e & 63;
        const int f = mt * 16 + (L & 15);
        float inv = 0.f, bias = 0.f;
        if (f < NF_) {
            inv = p.tbn_g[f] / sqrtf(p.tbn_v[f] + eps);
            bias = p.tconv_b[f] * inv + p.tbn_b[f] - p.tbn_m[f] * inv;
        }
        unsigned short* dst = ((unsigned short*)(ws + OFF_W1A)) + e * 8;
#pragma unroll
        for (int j = 0; j < 8; ++j) {
            const int k = (L >> 4) * 8 + j;
            float v = 0.f;
            if (f < NF_) {
                if (k < 25) v = p.tconv_w[f * 25 + k] * inv;
                else if (k == 25) v = bias;
            }
            dst[j] = (unsigned short)bfr(v);
        }
    }
    // scan A-frag panels (hi/lo bf16): which=0: [M0|0], which=1: [wx1|M1]
    // M0 = L0@L0^T - exp(ll0) I ; M1 likewise. Lane L: m=L&15, k=(L>>4)*8+j.
    for (int e = tid; e < 128; e += stride) {
        const int which = e >> 6;
        const int L = e & 63;
        const int m = L & 15;
        unsigned short* hi = ((unsigned short*)(ws + OFF_SA)) + (which * 2) * 512 + L * 8;
        unsigned short* lo = ((unsigned short*)(ws + OFF_SA)) + (which * 2 + 1) * 512 + L * 8;
#pragma unroll
        for (int j = 0; j < 8; ++j) {
            const int k = (L >> 4) * 8 + j;
            float v = 0.f;
            if (which == 0) {
                if (k < 16) {
                    float a = 0.f;
                    for (int i = 0; i < 16; ++i)
                        a = fmaf(p.L0[m * 16 + i], p.L0[k * 16 + i], a);
                    if (m == k) a -= expf(p.ll0[0]);
                    v = a;
                }
            } else {
                if (k < 16) {
                    v = p.wx1[m * 16 + k];
                } else {
                    const int k2 = k - 16;
                    float a = 0.f;
                    for (int i = 0; i < 16; ++i)
                        a = fmaf(p.L1[m * 16 + i], p.L1[k2 * 16 + i], a);
                    if (m == k2) a -= expf(p.ll1[0]);
                    v = a;
                }
            }
            const unsigned hu = bfr(v);
            hi[j] = (unsigned short)hu;
            const float lof = v - __uint_as_float(hu << 16);
            lo[j] = (unsigned short)bfr(lof);
        }
    }
    for (int f = tid; f < NF_; f += stride) {
        const float sinv = p.sbn_g[f] / sqrtf(p.sbn_v[f] + eps);
        ws[OFF_SB2 + f] = p.sconv_b[f] * sinv + p.sbn_b[f] - p.sbn_m[f] * sinv;
    }
    for (int e = tid; e < 3200; e += stride) {
        const int g = e / 40;
        const float pinv = p.pbn_g[g] / sqrtf(p.pbn_v[g] + eps);
        ws[OFF_PWC + e] = p.pw_w[e] * pinv;
    }
    for (int g = tid; g < 80; g += stride) {
        const float pinv = p.pbn_g[g] / sqrtf(p.pbn_v[g] + eps);
        ws[OFF_PB2 + g] = p.pw_b[g] * pinv + p.pbn_b[g] - p.pbn_m[g] * pinv;
    }
    for (int e = tid; e < 1280; e += stride) {
        const int k = e / 80, g = e - k * 80;
        float a = 0.f;
        for (int ee = 0; ee < ED_; ++ee)
            a = fmaf(p.wx0[k * ED_ + ee], p.proj_w[ee * 80 + g], a);
        ws[OFF_WP + e] = a;
    }
    for (int k = tid; k < K_; k += stride) {
        float a = p.b0[k];
        for (int ee = 0; ee < ED_; ++ee)
            a = fmaf(p.wx0[k * ED_ + ee], p.proj_b[ee], a);
        ws[OFF_BP + k] = a;
    }
}

// Prepack sconv weights * sbn scale into bf16 MFMA A-fragment order.
__global__ __launch_bounds__(256) void k0b_repack(
    const float* __restrict__ sconv_w, const float* __restrict__ sbn_g,
    const float* __restrict__ sbn_v, unsigned short* __restrict__ w2b) {
    const int e = blockIdx.x * 256 + threadIdx.x;
    if (e >= C_ * 3 * 2 * 64) return;
    const int c = e / 384;
    int r = e - c * 384;
    const int mt = r >> 7; r &= 127;
    const int kc = r >> 6;
    const int lane = r & 63;
    const int g = mt * 16 + (lane & 15);
    const float sinv = (g < NF_) ? sbn_g[g] * rsqrtf(sbn_v[g] + 1e-5f) : 0.f;
    unsigned short o[8];
#pragma unroll
    for (int j = 0; j < 8; ++j) {
        const int f = kc * 32 + (lane >> 4) * 8 + j;
        float v = 0.f;
        if (g < NF_ && f < NF_) v = sconv_w[g * (NF_ * C_) + f * C_ + c] * sinv;
        o[j] = (unsigned short)bfr(v);
    }
    unsigned short* dst = w2b + (size_t)e * 8;
#pragma unroll
    for (int j = 0; j < 8; ++j) dst[j] = o[j];
}

// zero the raw accumulator (ws is re-poisoned 0xAA before every launch)
__global__ __launch_bounds__(256) void k1z(float4* __restrict__ p) {
    const int i = blockIdx.x * 256 + threadIdx.x;
    if (i < 320000) p[i] = make_float4(0.f, 0.f, 0.f, 0.f);
}

// Both convs on MFMA (round-7 verified, unchanged).
__global__ __launch_bounds__(256, 3) void k1_mfma(
    const float* __restrict__ x, const unsigned short* __restrict__ w1a,
    const unsigned short* __restrict__ w2b, float* __restrict__ s2raw) {
    __shared__ float xs[17 * XROW];
    __shared__ unsigned int vsI[8192];

    const int tid = threadIdx.x;
    const int split = blockIdx.x & 7;
    const int tile = (blockIdx.x >> 3) & 7;
    const int b = blockIdx.x >> 6;
    const int c0 = (split * C_) >> 3;
    const int c1 = ((split + 1) * C_) >> 3;
    const int cc = c1 - c0;
    const int t0 = tile << 8;
    const int w = tid >> 6;
    const int lane = tid & 63;
    const int n = lane & 15;
    const int q = lane >> 4;
    const int qh = q >> 1;
    const int q1_2 = (q & 1) * 2;
    const bool q3 = (q == 3);
    const int wb = w << 11;
    const int w64 = w << 6;
    const int ln8 = n + q * 8;

    for (int i = tid; i < 8192; i += 256) vsI[i] = 0u;
    for (int e = tid; e < cc * XROW; e += 256) {
        const int cl = e / XROW;
        const int i = e - cl * XROW;
        const int t = t0 - 12 + i;
        float v = 0.f;
        if ((unsigned)t < (unsigned)T_) v = x[(b * C_ + c0 + cl) * T_ + t];
        xs[e] = v;
    }
    __syncthreads();

    const s8v* w1a8 = (const s8v*)w1a;
    s8v wA[3];
#pragma unroll
    for (int mt = 0; mt < 3; ++mt) wA[mt] = w1a8[mt * 64 + lane];

    f4v acc[4][3];
#pragma unroll
    for (int nt = 0; nt < 4; ++nt)
#pragma unroll
        for (int mt = 0; mt < 3; ++mt) acc[nt][mt] = (f4v)0.f;

    const s8v* w2b8 = (const s8v*)w2b;
    const f4v z4 = (f4v)0.f;

    for (int cl = 0; cl < cc; ++cl) {
        const int c = c0 + cl;
        s8v af[3][2];
#pragma unroll
        for (int mt = 0; mt < 3; ++mt)
#pragma unroll
            for (int kc = 0; kc < 2; ++kc)
                af[mt][kc] = w2b8[((c * 3 + mt) * 2 + kc) * 64 + lane];

        const float* xrow = &xs[cl * XROW + w64 + ln8];

#pragma unroll
        for (int nt = 0; nt < 4; ++nt) {
            float bx[8];
#pragma unroll
            for (int j = 0; j < 8; ++j) bx[j] = xrow[nt * 16 + j];
            if (q3) bx[1] = 1.0f;
            unsigned pw_[4];
#pragma unroll
            for (int jj = 0; jj < 4; ++jj)
                pw_[jj] = bfr(bx[2 * jj]) |
                    ((__float_as_uint(bx[2 * jj + 1]) + 0x8000u) & 0xFFFF0000u);
            const s8v bh = *(const s8v*)pw_;
#pragma unroll
            for (int mt = 0; mt < 3; ++mt) {
                const f4v vT = __builtin_amdgcn_mfma_f32_16x16x32_bf16(
                    wA[mt], bh, z4, 0, 0, 0);
                const float e0 = elu_f(vT[0]);
                const float e1 = elu_f(vT[1]);
                const float e2 = elu_f(vT[2]);
                const float e3 = elu_f(vT[3]);
                const unsigned lo = bfr(e0) |
                    ((__float_as_uint(e1) + 0x8000u) & 0xFFFF0000u);
                const unsigned hi = bfr(e2) |
                    ((__float_as_uint(e3) + 0x8000u) & 0xFFFF0000u);
                const int base = wb + ((nt * 8 + 2 * mt + qh) << 6) + (n << 2) + q1_2;
                vsI[base] = lo;
                vsI[base + 1] = hi;
            }
        }
        __builtin_amdgcn_wave_barrier();

#pragma unroll
        for (int nt = 0; nt < 4; ++nt) {
            const s8v b0 = *(const s8v*)&vsI[wb + ((nt * 8 + q) << 6) + (n << 2)];
            const s8v b1 = *(const s8v*)&vsI[wb + ((nt * 8 + 4 + q) << 6) + (n << 2)];
#pragma unroll
            for (int mt = 0; mt < 3; ++mt) {
                acc[nt][mt] = __builtin_amdgcn_mfma_f32_16x16x32_bf16(
                    af[mt][0], b0, acc[nt][mt], 0, 0, 0);
                acc[nt][mt] = __builtin_amdgcn_mfma_f32_16x16x32_bf16(
                    af[mt][1], b1, acc[nt][mt], 0, 0, 0);
            }
        }
        __builtin_amdgcn_wave_barrier();
    }

#pragma unroll
    for (int nt = 0; nt < 4; ++nt) {
        const int t = t0 + w * 64 + nt * 16 + n;
        if (t >= T_) continue;
#pragma unroll
        for (int mt = 0; mt < 3; ++mt) {
#pragma unroll
            for (int r = 0; r < 4; ++r) {
                const int g = mt * 16 + q * 4 + r;
                if (g < NF_)
                    atomicAdd(&s2raw[(b * NF_ + g) * T_ + t], acc[nt][mt][r]);
            }
        }
    }
}

// Fused dw/pw/pool/proj (round-7 verified, unchanged).
__global__ __launch_bounds__(256) void k2_dwpw(
    const float* __restrict__ s2raw, const float* __restrict__ sb2,
    const float* __restrict__ dw_w, const float* __restrict__ dw_b,
    const float* __restrict__ pwc, const float* __restrict__ pb2,
    const float* __restrict__ WP, const float* __restrict__ bp,
    float* __restrict__ xp) {
    __shared__ float st[NF_ * 114];
    __shared__ float dwo[NF_ * 100];
    __shared__ float dwwl[NF_ * 15];
    __shared__ float dwbl[NF_];
    __shared__ float pwcl[80 * 40];
    __shared__ float pb2l[80];
    __shared__ float WPl[K_ * 80];
    __shared__ float bpl[K_];
    __shared__ float po[80 * 25];
    const int tid = threadIdx.x;
    const int b = blockIdx.x / 20;
    const int tp0 = (blockIdx.x % 20) * 25;
    const int tbase = tp0 * 4 - 7;
    for (int e = tid; e < NF_ * 114; e += 256) {
        const int f = e / 114;
        const int i = e - f * 114;
        const int t = tbase + i;
        float v = 0.f;
        if ((unsigned)t < (unsigned)T_)
            v = elu_f(s2raw[(b * NF_ + f) * T_ + t] + sb2[f]);
        st[e] = v;
    }
    for (int e = tid; e < 600; e += 256) dwwl[e] = dw_w[e];
    for (int e = tid; e < 3200; e += 256) pwcl[e] = pwc[e];
    for (int e = tid; e < 1280; e += 256) WPl[e] = WP[e];
    if (tid < NF_) dwbl[tid] = dw_b[tid];
    if (tid < 80) pb2l[tid] = pb2[tid];
    if (tid < K_) bpl[tid] = bp[tid];
    __syncthreads();
    for (int e = tid; e < 4000; e += 256) {
        const int f = e / 100;
        const int tq = e - f * 100;
        float a = dwbl[f];
#pragma unroll
        for (int kk = 0; kk < 15; ++kk)
            a = fmaf(dwwl[f * 15 + kk], st[f * 114 + tq + kk], a);
        dwo[e] = a;
    }
    __syncthreads();
    for (int e = tid; e < 2000; e += 256) {
        const int g = e / 25;
        const int tp = e - g * 25;
        float sum = 0.f;
#pragma unroll
        for (int dt = 0; dt < 4; ++dt) {
            float a = pb2l[g];
            for (int f = 0; f < NF_; ++f)
                a = fmaf(pwcl[g * 40 + f], dwo[f * 100 + tp * 4 + dt], a);
            sum += elu_f(a);
        }
        po[e] = sum * 0.25f;
    }
    __syncthreads();
    for (int e = tid; e < 400; e += 256) {
        const int tp = e >> 4;
        const int k = e & 15;
        float a = bpl[k];
        for (int g = 0; g < 80; ++g)
            a = fmaf(WPl[k * 80 + g], po[g * 25 + tp], a);
        xp[(b * TP_ + tp0 + tp) * K_ + k] = a;
    }
}

// MFMA scan: one wave, all 16 batches. Per step both cells fused:
// [pre0_{t+1}; pre1_t] = [[M0,0],[wx1,M1]] @ [h0_t; h1_{t-1}] via
// 16x16x32 bf16 MFMA with hi/lo split compensation (Ah*Bh + Ah*Bl + Al*Bh).
// B built via LDS round-trip (pairs layout, 20-dword row pad). LN sums via
// in-lane adds + shfl_xor(16) + shfl_xor(32). tanh = 1-2*rcp(exp(2x)+1).
__global__ __launch_bounds__(64, 1) void k3_scan(
    const float* __restrict__ xp, const unsigned short* __restrict__ sa,
    const float* __restrict__ b1, const float* __restrict__ ln0_g,
    const float* __restrict__ ln0_b, const float* __restrict__ ln1_g,
    const float* __restrict__ ln1_b, float* __restrict__ out) {
    __shared__ unsigned int ldsU[640];   // hi panel [16][20], lo panel +320
    const int L = threadIdx.x;
    const int n = L & 15;
    const int q = L >> 4;

    const s8v* A8 = (const s8v*)sa;
    const s8v a1h = A8[L];
    const s8v a1l = A8[64 + L];
    const s8v a2h = A8[128 + L];
    const s8v a2l = A8[192 + L];

    const float4 b1l = *(const float4*)&b1[4 * q];
    const float4 g0v = *(const float4*)&ln0_g[4 * q];
    const float4 e0v = *(const float4*)&ln0_b[4 * q];
    const float4 g1v = *(const float4*)&ln1_g[4 * q];
    const float4 e1v = *(const float4*)&ln1_b[4 * q];
    // prefold the tanh 2x into LN affine
    const float g20[4] = {2.f * g0v.x, 2.f * g0v.y, 2.f * g0v.z, 2.f * g0v.w};
    const float b20[4] = {2.f * e0v.x, 2.f * e0v.y, 2.f * e0v.z, 2.f * e0v.w};
    const float g21[4] = {2.f * g1v.x, 2.f * g1v.y, 2.f * g1v.z, 2.f * g1v.w};
    const float b21[4] = {2.f * e1v.x, 2.f * e1v.y, 2.f * e1v.z, 2.f * e1v.w};

    const float* xb = xp + n * (TP_ * K_) + 4 * q;
    const float4 x0 = *(const float4*)&xb[0];
    float4 xr4[4];
    xr4[1] = *(const float4*)&xb[1 * 16];
    xr4[2] = *(const float4*)&xb[2 * 16];
    xr4[3] = *(const float4*)&xb[3 * 16];
    xr4[0] = *(const float4*)&xb[4 * 16];

    float h0c[4], h1c[4];
    {   // prologue: h0_0 = tanh(LN(x_0)); h1 = 0
        float pr[4] = {x0.x, x0.y, x0.z, x0.w};
        float s1 = (pr[0] + pr[1]) + (pr[2] + pr[3]);
        float s2 = fmaf(pr[0], pr[0],
                   fmaf(pr[1], pr[1], fmaf(pr[2], pr[2], pr[3] * pr[3])));
        s1 += __shfl_xor(s1, 16, 64); s2 += __shfl_xor(s2, 16, 64);
        s1 += __shfl_xor(s1, 32, 64); s2 += __shfl_xor(s2, 32, 64);
        const float mu = s1 * 0.0625f;
        const float var = fmaf(s2, 0.0625f, -mu * mu);
        const float rr = rsqrtf(var + 1e-5f);
#pragma unroll
        for (int r = 0; r < 4; ++r) {
            const float arg = fmaf((pr[r] - mu) * rr, g20[r], b20[r]);
            const float ex = __expf(arg);
            const float rc = __builtin_amdgcn_rcpf(ex + 1.f);
            h0c[r] = fmaf(-2.f, rc, 1.f);
            h1c[r] = 0.f;
        }
    }

    const int wa = n * 20 + 2 * q;
    const int ra = n * 20 + 4 * q;
    const f4v z4 = (f4v)0.f;

    for (int t = 0; t < TP_; ++t) {
        // pack h0,h1 into hi/lo bf16 pairs
        unsigned hp[4], lp[4];
        {
            const unsigned u0 = bfr(h0c[0]);
            const unsigned u1h = (__float_as_uint(h0c[1]) + 0x8000u) & 0xFFFF0000u;
            hp[0] = u0 | u1h;
            lp[0] = bfr(h0c[0] - __uint_as_float(u0 << 16)) |
                ((__float_as_uint(h0c[1] - __uint_as_float(u1h)) + 0x8000u) & 0xFFFF0000u);
            const unsigned u2 = bfr(h0c[2]);
            const unsigned u3h = (__float_as_uint(h0c[3]) + 0x8000u) & 0xFFFF0000u;
            hp[1] = u2 | u3h;
            lp[1] = bfr(h0c[2] - __uint_as_float(u2 << 16)) |
                ((__float_as_uint(h0c[3] - __uint_as_float(u3h)) + 0x8000u) & 0xFFFF0000u);
            const unsigned v0 = bfr(h1c[0]);
            const unsigned v1h = (__float_as_uint(h1c[1]) + 0x8000u) & 0xFFFF0000u;
            hp[2] = v0 | v1h;
            lp[2] = bfr(h1c[0] - __uint_as_float(v0 << 16)) |
                ((__float_as_uint(h1c[1] - __uint_as_float(v1h)) + 0x8000u) & 0xFFFF0000u);
            const unsigned v2 = bfr(h1c[2]);
            const unsigned v3h = (__float_as_uint(h1c[3]) + 0x8000u) & 0xFFFF0000u;
            hp[3] = v2 | v3h;
            lp[3] = bfr(h1c[2] - __uint_as_float(v2 << 16)) |
                ((__float_as_uint(h1c[3] - __uint_as_float(v3h)) + 0x8000u) & 0xFFFF0000u);
        }
        *(uint2*)&ldsU[wa] = make_uint2(hp[0], hp[1]);
        *(uint2*)&ldsU[wa + 8] = make_uint2(hp[2], hp[3]);
        *(uint2*)&ldsU[320 + wa] = make_uint2(lp[0], lp[1]);
        *(uint2*)&ldsU[320 + wa + 8] = make_uint2(lp[2], lp[3]);
        __builtin_amdgcn_wave_barrier();
        const s8v Bhi = *(const s8v*)&ldsU[ra];
        const s8v Blo = *(const s8v*)&ldsU[320 + ra];
        __builtin_amdgcn_wave_barrier();

        f4v D0 = __builtin_amdgcn_mfma_f32_16x16x32_bf16(a1h, Bhi, z4, 0, 0, 0);
        D0 = __builtin_amdgcn_mfma_f32_16x16x32_bf16(a1l, Bhi, D0, 0, 0, 0);
        D0 = __builtin_amdgcn_mfma_f32_16x16x32_bf16(a1h, Blo, D0, 0, 0, 0);
        f4v D1 = __builtin_amdgcn_mfma_f32_16x16x32_bf16(a2h, Bhi, z4, 0, 0, 0);
        D1 = __builtin_amdgcn_mfma_f32_16x16x32_bf16(a2l, Bhi, D1, 0, 0, 0);
        D1 = __builtin_amdgcn_mfma_f32_16x16x32_bf16(a2h, Blo, D1, 0, 0, 0);

        const int slot = (t + 1) & 3;
        const float4 xv = xr4[slot];
        int tf = t + 5;
        if (tf > TP_ - 1) tf = TP_ - 1;
        xr4[slot] = *(const float4*)&xb[tf * 16];

        float p0[4] = {D0[0] + xv.x, D0[1] + xv.y, D0[2] + xv.z, D0[3] + xv.w};
        float p1[4] = {D1[0] + b1l.x, D1[1] + b1l.y, D1[2] + b1l.z, D1[3] + b1l.w};

        float s1 = (p0[0] + p0[1]) + (p0[2] + p0[3]);
        float s2 = fmaf(p0[0], p0[0],
                   fmaf(p0[1], p0[1], fmaf(p0[2], p0[2], p0[3] * p0[3])));
        float u1 = (p1[0] + p1[1]) + (p1[2] + p1[3]);
        float u2 = fmaf(p1[0], p1[0],
                   fmaf(p1[1], p1[1], fmaf(p1[2], p1[2], p1[3] * p1[3])));
        s1 += __shfl_xor(s1, 16, 64); s2 += __shfl_xor(s2, 16, 64);
        u1 += __shfl_xor(u1, 16, 64); u2 += __shfl_xor(u2, 16, 64);
        s1 += __shfl_xor(s1, 32, 64); s2 += __shfl_xor(s2, 32, 64);
        u1 += __shfl_xor(u1, 32, 64); u2 += __shfl_xor(u2, 32, 64);

        const float mu0 = s1 * 0.0625f;
        const float var0 = fmaf(s2, 0.0625f, -mu0 * mu0);
        const float r0 = rsqrtf(var0 + 1e-5f);
        const float mu1 = u1 * 0.0625f;
        const float var1 = fmaf(u2, 0.0625f, -mu1 * mu1);
        const float r1 = rsqrtf(var1 + 1e-5f);
#pragma unroll
        for (int r = 0; r < 4; ++r) {
            const float a0 = fmaf((p0[r] - mu0) * r0, g20[r], b20[r]);
            const float x0e = __expf(a0);
            const float rc0 = __builtin_amdgcn_rcpf(x0e + 1.f);
            h0c[r] = fmaf(-2.f, rc0, 1.f);
            const float a1 = fmaf((p1[r] - mu1) * r1, g21[r], b21[r]);
            const float x1e = __expf(a1);
            const float rc1 = __builtin_amdgcn_rcpf(x1e + 1.f);
            h1c[r] = fmaf(-2.f, rc1, 1.f);
        }
    }
    *(float4*)&out[n * 16 + 4 * q] = make_float4(h1c[0], h1c[1], h1c[2], h1c[3]);
    if (q == 0) out[256 + n] = 1.0f;    // alpha = softmax over size-1 axis
}

extern "C" void kernel_launch(void* const* d_in, const int* in_sizes, int n_in,
                              void* d_out, int out_size, void* d_ws, size_t ws_size,
                              hipStream_t stream) {
    const float* x       = (const float*)d_in[0];
    const float* sconv_w = (const float*)d_in[7];
    const float* sbn_g   = (const float*)d_in[9];
    const float* sbn_v   = (const float*)d_in[12];
    const float* dw_w    = (const float*)d_in[13];
    const float* dw_b    = (const float*)d_in[14];
    const float* b1      = (const float*)d_in[32];
    const float* ln0_g   = (const float*)d_in[27];
    const float* ln0_b   = (const float*)d_in[28];
    const float* ln1_g   = (const float*)d_in[33];
    const float* ln1_b   = (const float*)d_in[34];
    float* ws = (float*)d_ws;
    float* out = (float*)d_out;

    P0 p;
    p.tconv_w = (const float*)d_in[1]; p.tconv_b = (const float*)d_in[2];
    p.tbn_g = (const float*)d_in[3]; p.tbn_b = (const float*)d_in[4];
    p.tbn_m = (const float*)d_in[5]; p.tbn_v = (const float*)d_in[6];
    p.sconv_b = (const float*)d_in[8];
    p.sbn_g = sbn_g; p.sbn_b = (const float*)d_in[10];
    p.sbn_m = (const float*)d_in[11]; p.sbn_v = sbn_v;
    p.pw_w = (const float*)d_in[15]; p.pw_b = (const float*)d_in[16];
    p.pbn_g = (const float*)d_in[17]; p.pbn_b = (const float*)d_in[18];
    p.pbn_m = (const float*)d_in[19]; p.pbn_v = (const float*)d_in[20];
    p.proj_w = (const float*)d_in[21]; p.proj_b = (const float*)d_in[22];
    p.wx0 = (const float*)d_in[23]; p.b0 = (const float*)d_in[26];
    p.L0 = (const float*)d_in[24]; p.ll0 = (const float*)d_in[25];
    p.L1 = (const float*)d_in[30]; p.ll1 = (const float*)d_in[31];
    p.wx1 = (const float*)d_in[29];
    p.ws = ws;

    unsigned short* w2b = (unsigned short*)(ws + OFF_W2U);
    unsigned short* w1a = (unsigned short*)(ws + OFF_W1A);

    k0a_setup<<<dim3(8), dim3(256), 0, stream>>>(p);
    k0b_repack<<<dim3(194), dim3(256), 0, stream>>>(sconv_w, sbn_g, sbn_v, w2b);
    k1z<<<dim3(1250), dim3(256), 0, stream>>>((float4*)(ws + OFF_S2R));
    k1_mfma<<<dim3(1024), dim3(256), 0, stream>>>(x, w1a, w2b, ws + OFF_S2R);
    k2_dwpw<<<dim3(320), dim3(256), 0, stream>>>(ws + OFF_S2R, ws + OFF_SB2,
                                                 dw_w, dw_b, ws + OFF_PWC,
                                                 ws + OFF_PB2, ws + OFF_WP, ws + OFF_BP,
                                                 ws + OFF_XP);
    k3_scan<<<dim3(1), dim3(64), 0, stream>>>(ws + OFF_XP,
                                              (const unsigned short*)(ws + OFF_SA),
                                              b1, ln0_g, ln0_b, ln1_g, ln1_b, out);
}